// Round 1
// baseline (900.705 us; speedup 1.0000x reference)
//
#include <hip/hip_runtime.h>

// Problem dims
constexpr int NS   = 16;    // batch
constexpr int DIM  = 32;    // in_dim == out_dim
constexpr int FEA  = 192;   // in_f == out_f
constexpr int ELEMS = DIM * FEA;   // 6144 per sample

// epass tiling
constexpr int SPLIT   = 4;              // f-splits per o
constexpr int FPB     = FEA / SPLIT;    // 48 f per block
constexpr int FCHUNK  = 16;             // f per LDS stage
constexpr int NCHUNKS = FPB / FCHUNK;   // 3
constexpr int ROWPAD  = 20;             // 16 floats (n) + 4 pad -> conflict-free i-reads

__device__ __forceinline__ void fma4(float4& a, float x, const float4& t) {
    a.x = fmaf(x, t.x, a.x);
    a.y = fmaf(x, t.y, a.y);
    a.z = fmaf(x, t.z, a.z);
    a.w = fmaf(x, t.w, a.w);
}

// Generic weighted contraction:
//   y[n, D, O] = sum_{I=0..31, F=0..191} X[n,I,F] * W[I][F][O][D] * A[F][O]
// W layout: [32][192][192][32] (D contiguous)   — matches both s2t and t2s
// xt layout: [F][I][n] (n contiguous, 16)       — transposed activations
// A  layout: [F][O] row-major (192 cols)
// Output partials: out[s][O][n*32+D]  (s = f-split index), 512 floats per (s,O)
template <bool DUAL>
__global__ __launch_bounds__(256, 2) void epass_kernel(
    const float* __restrict__ W, const float* __restrict__ xt,
    const float* __restrict__ A1, const float* __restrict__ A2,
    float* __restrict__ outA, float* __restrict__ outB)
{
    __shared__ float smem[FCHUNK * DIM * ROWPAD];  // 10240 floats (40 KB), reused for reduce
    __shared__ float acol[2][FPB];

    const int tid = threadIdx.x;
    const int o   = blockIdx.x >> 2;          // output O index
    const int s   = blockIdx.x & (SPLIT - 1); // f-split
    const int i   = tid >> 3;                 // contraction I (0..31)
    const int dq  = tid & 7;                  // D quad (0..7)
    const int fBase = s * FPB;

    // Preload A column(s) for this o, f-range
    for (int j = tid; j < FPB; j += 256) {
        acol[0][j] = A1[(fBase + j) * FEA + o];
        if (DUAL) acol[1][j] = A2[(fBase + j) * FEA + o];
    }

    float4 accA[16];
    float4 accB[16];
#pragma unroll
    for (int n = 0; n < 16; ++n) {
        accA[n] = make_float4(0.f, 0.f, 0.f, 0.f);
        if (DUAL) accB[n] = make_float4(0.f, 0.f, 0.f, 0.f);
    }

    const float* wp = W + (size_t)(((i * FEA + fBase) * FEA + o) * DIM + dq * 4);

    for (int c = 0; c < NCHUNKS; ++c) {
        __syncthreads();
        // Stage x chunk: 16 f x 32 i x 16 n = 8192 floats, contiguous in xt
        const float4* src = (const float4*)(xt + (size_t)(fBase + c * FCHUNK) * (DIM * NS));
#pragma unroll
        for (int q = 0; q < 8; ++q) {
            int lin = q * 256 + tid;            // quad index
            float4 v = src[lin];
            *(float4*)&smem[(lin >> 2) * ROWPAD + (lin & 3) * 4] = v;
        }
        __syncthreads();

        float4 tnext = *(const float4*)wp;
        for (int fl = 0; fl < FCHUNK; ++fl) {
            float4 t4 = tnext;
            wp += FEA * DIM;                    // advance one f (6144 floats)
            if (fl != FCHUNK - 1) tnext = *(const float4*)wp;

            const float a1 = acol[0][c * FCHUNK + fl];
            float4 ta = make_float4(t4.x * a1, t4.y * a1, t4.z * a1, t4.w * a1);
            float4 tb;
            if (DUAL) {
                const float a2 = acol[1][c * FCHUNK + fl];
                tb = make_float4(t4.x * a2, t4.y * a2, t4.z * a2, t4.w * a2);
            }

            const float* xr = &smem[(fl * DIM + i) * ROWPAD];
#pragma unroll
            for (int nq = 0; nq < 4; ++nq) {
                float4 xv = *(const float4*)(xr + nq * 4);
                fma4(accA[nq * 4 + 0], xv.x, ta);
                fma4(accA[nq * 4 + 1], xv.y, ta);
                fma4(accA[nq * 4 + 2], xv.z, ta);
                fma4(accA[nq * 4 + 3], xv.w, ta);
                if (DUAL) {
                    fma4(accB[nq * 4 + 0], xv.x, tb);
                    fma4(accB[nq * 4 + 1], xv.y, tb);
                    fma4(accB[nq * 4 + 2], xv.z, tb);
                    fma4(accB[nq * 4 + 3], xv.w, tb);
                }
            }
        }
    }

    // Reduce over the 8 i's within each wave (lane bits 3..5 hold low i bits)
#pragma unroll
    for (int m = 8; m <= 32; m <<= 1) {
#pragma unroll
        for (int n = 0; n < 16; ++n) {
            accA[n].x += __shfl_xor(accA[n].x, m);
            accA[n].y += __shfl_xor(accA[n].y, m);
            accA[n].z += __shfl_xor(accA[n].z, m);
            accA[n].w += __shfl_xor(accA[n].w, m);
            if (DUAL) {
                accB[n].x += __shfl_xor(accB[n].x, m);
                accB[n].y += __shfl_xor(accB[n].y, m);
                accB[n].z += __shfl_xor(accB[n].z, m);
                accB[n].w += __shfl_xor(accB[n].w, m);
            }
        }
    }

    const int lane = tid & 63;
    const int w    = tid >> 6;
    float* red = smem;  // reuse: 4 waves x 8 dq x 16 n x 4 = 2048 floats

    __syncthreads();
    if (lane < 8) {
#pragma unroll
        for (int n = 0; n < 16; ++n)
            *(float4*)&red[((w * 8 + lane) * 16 + n) * 4] = accA[n];
    }
    __syncthreads();
    {
        float* dst = outA + (size_t)(s * FEA + o) * (NS * DIM);
        for (int h = tid; h < NS * DIM; h += 256) {
            int n = h >> 5, d = h & 31;
            float v = 0.f;
#pragma unroll
            for (int ww = 0; ww < 4; ++ww)
                v += red[((ww * 8 + (d >> 2)) * 16 + n) * 4 + (d & 3)];
            dst[h] = v;
        }
    }
    if (DUAL) {
        __syncthreads();
        if (lane < 8) {
#pragma unroll
            for (int n = 0; n < 16; ++n)
                *(float4*)&red[((w * 8 + lane) * 16 + n) * 4] = accB[n];
        }
        __syncthreads();
        {
            float* dst = outB + (size_t)(s * FEA + o) * (NS * DIM);
            for (int h = tid; h < NS * DIM; h += 256) {
                int n = h >> 5, d = h & 31;
                float v = 0.f;
#pragma unroll
                for (int ww = 0; ww < 4; ++ww)
                    v += red[((ww * 8 + (d >> 2)) * 16 + n) * 4 + (d & 3)];
                dst[h] = v;
            }
        }
    }
}

// ---- small helpers -------------------------------------------------------

__device__ __forceinline__ float2 block_meanrstd(float s1, float s2, int tid, float* red8) {
#pragma unroll
    for (int m = 1; m < 64; m <<= 1) {
        s1 += __shfl_xor(s1, m);
        s2 += __shfl_xor(s2, m);
    }
    if ((tid & 63) == 0) {
        red8[(tid >> 6) * 2]     = s1;
        red8[(tid >> 6) * 2 + 1] = s2;
    }
    __syncthreads();
    s1 = red8[0] + red8[2] + red8[4] + red8[6];
    s2 = red8[1] + red8[3] + red8[5] + red8[7];
    float mean = s1 * (1.0f / ELEMS);
    float var  = s2 * (1.0f / ELEMS) - mean * mean;
    return make_float2(mean, rsqrtf(var + 1e-5f));
}

// h1 = LN(sum_s pA); writes natural [n][D][O] and transposed [O][D][n]
__global__ __launch_bounds__(256) void reduce_ln_h1(
    const float* __restrict__ p, float* __restrict__ h1, float* __restrict__ h1t)
{
    __shared__ float vals[ELEMS];
    __shared__ float red8[8];
    const int n = blockIdx.x, tid = threadIdx.x;
    float s1 = 0.f, s2 = 0.f;
    for (int e = tid; e < ELEMS; e += 256) {
        int d = e / FEA, o = e % FEA;
        float v = 0.f;
#pragma unroll
        for (int sp = 0; sp < SPLIT; ++sp)
            v += p[(size_t)(sp * FEA + o) * (NS * DIM) + n * DIM + d];
        vals[e] = v; s1 += v; s2 += v * v;
    }
    float2 mr = block_meanrstd(s1, s2, tid, red8);
    for (int e = tid; e < ELEMS; e += 256) {
        float v = (vals[e] - mr.x) * mr.y;
        h1[n * ELEMS + e] = v;
        int d = e / FEA, o = e % FEA;
        h1t[(o * DIM + d) * NS + n] = v;
    }
}

// h2 = LN(0.5*(xs1 + sum_s pC)); writes transposed only
__global__ __launch_bounds__(256) void reduce_ln_h2(
    const float* __restrict__ p, const float* __restrict__ xs1, float* __restrict__ h2t)
{
    __shared__ float vals[ELEMS];
    __shared__ float red8[8];
    const int n = blockIdx.x, tid = threadIdx.x;
    float s1 = 0.f, s2 = 0.f;
    for (int e = tid; e < ELEMS; e += 256) {
        int d = e / FEA, o = e % FEA;
        float v = 0.f;
#pragma unroll
        for (int sp = 0; sp < SPLIT; ++sp)
            v += p[(size_t)(sp * FEA + o) * (NS * DIM) + n * DIM + d];
        v = 0.5f * (v + xs1[n * ELEMS + e]);
        vals[e] = v; s1 += v; s2 += v * v;
    }
    float2 mr = block_meanrstd(s1, s2, tid, red8);
    for (int e = tid; e < ELEMS; e += 256) {
        float v = (vals[e] - mr.x) * mr.y;
        int d = e / FEA, o = e % FEA;
        h2t[(o * DIM + d) * NS + n] = v;
    }
}

// out = LN((sum_s pB + h1t1 + sum_s pD)/3); natural layout
__global__ __launch_bounds__(256) void final_ln(
    const float* __restrict__ pB, const float* __restrict__ pD,
    const float* __restrict__ h1t1, float* __restrict__ out)
{
    __shared__ float vals[ELEMS];
    __shared__ float red8[8];
    const int n = blockIdx.x, tid = threadIdx.x;
    float s1 = 0.f, s2 = 0.f;
    for (int e = tid; e < ELEMS; e += 256) {
        int d = e / FEA, o = e % FEA;
        float v = 0.f;
#pragma unroll
        for (int sp = 0; sp < SPLIT; ++sp) {
            v += pB[(size_t)(sp * FEA + o) * (NS * DIM) + n * DIM + d];
            v += pD[(size_t)(sp * FEA + o) * (NS * DIM) + n * DIM + d];
        }
        v = (v + h1t1[n * ELEMS + e]) * (1.0f / 3.0f);
        vals[e] = v; s1 += v; s2 += v * v;
    }
    float2 mr = block_meanrstd(s1, s2, tid, red8);
    for (int e = tid; e < ELEMS; e += 256) {
        out[n * ELEMS + e] = (vals[e] - mr.x) * mr.y;
    }
}

// xt[(f*32+i)*16+n] = x[(n*32+i)*192+f]
__global__ __launch_bounds__(256) void transpose_x(
    const float* __restrict__ x, float* __restrict__ xt)
{
    int idx = blockIdx.x * 256 + threadIdx.x;   // 98304 total
    int n = idx & 15;
    int r = idx >> 4;
    int i = r & 31;
    int f = r >> 5;
    xt[idx] = x[(n * 32 + i) * 192 + f];
}

// Y[r][j] = sum_f X[r][f] * M[f][j], 8 rows per block, 192 cols
__global__ __launch_bounds__(192) void mm192x8(
    const float* __restrict__ X, const float* __restrict__ M, float* __restrict__ Y)
{
    __shared__ float rows[8][192];
    const int rb = blockIdx.x * 8;
    const int j  = threadIdx.x;
#pragma unroll
    for (int k = 0; k < 8; ++k) rows[k][j] = X[(rb + k) * 192 + j];
    __syncthreads();
    float acc[8] = {0.f, 0.f, 0.f, 0.f, 0.f, 0.f, 0.f, 0.f};
    for (int f = 0; f < 192; ++f) {
        float m = M[f * 192 + j];
#pragma unroll
        for (int k = 0; k < 8; ++k) acc[k] = fmaf(rows[k][f], m, acc[k]);
    }
#pragma unroll
    for (int k = 0; k < 8; ++k) Y[(rb + k) * 192 + j] = acc[k];
}

extern "C" void kernel_launch(void* const* d_in, const int* in_sizes, int n_in,
                              void* d_out, int out_size, void* d_ws, size_t ws_size,
                              hipStream_t stream) {
    (void)in_sizes; (void)n_in; (void)out_size; (void)ws_size;
    const float* x   = (const float*)d_in[0];
    const float* s2t = (const float*)d_in[1];
    const float* t2s = (const float*)d_in[2];
    const float* s0  = (const float*)d_in[3];
    const float* s1  = (const float*)d_in[4];
    /* s2 = d_in[5] unused by the 4-layer schedule */
    const float* t0  = (const float*)d_in[6];
    const float* t1  = (const float*)d_in[7];
    const float* t2  = (const float*)d_in[8];
    float* out = (float*)d_out;

    float* ws = (float*)d_ws;
    float* xt   = ws; ws += 98304;
    float* xs1  = ws; ws += 98304;
    float* h1   = ws; ws += 98304;
    float* h1t  = ws; ws += 98304;
    float* h1t1 = ws; ws += 98304;
    float* h2t  = ws; ws += 98304;
    float* P    = ws; ws += SPLIT * FEA * NS * DIM;   // reused: pA -> pC -> pD
    float* pB   = ws; ws += SPLIT * FEA * NS * DIM;   // persists from E1 to final

    // Layer prep (depends only on x)
    transpose_x<<<384, 256, 0, stream>>>(x, xt);
    mm192x8<<<64, 192, 0, stream>>>(x, s1, xs1);          // xs1 = x @ s1

    // E1: one pass over s2t, two A-weighted outputs: (x,t0) -> h1 pre-LN, (x,t2) -> final term
    epass_kernel<true><<<768, 256, 0, stream>>>(s2t, xt, t0, t2, P, pB);
    reduce_ln_h1<<<16, 256, 0, stream>>>(P, h1, h1t);     // h1 = LN(sum P)

    mm192x8<<<64, 192, 0, stream>>>(h1, t1, h1t1);        // h1t1 = h1 @ t1

    // E2: pass over t2s with h1, A = s0
    epass_kernel<false><<<768, 256, 0, stream>>>(t2s, h1t, s0, nullptr, P, nullptr);
    reduce_ln_h2<<<16, 256, 0, stream>>>(P, xs1, h2t);    // h2 = LN(0.5*(xs1 + sum P))

    // E3: pass over s2t with h2, A = t0
    epass_kernel<false><<<768, 256, 0, stream>>>(s2t, h2t, t0, nullptr, P, nullptr);

    // out = LN((pB + h1@t1 + pD)/3)
    final_ln<<<16, 256, 0, stream>>>(pB, P, h1t1, out);
}